// Round 1
// baseline (449.638 us; speedup 1.0000x reference)
//
#include <hip/hip_runtime.h>
#include <stdint.h>

#define HID 512
#define NH 8
#define HD 64
#define BATCH 2
#define SEQ 4096
#define M_TOT (BATCH*SEQ)   // 8192

typedef __attribute__((ext_vector_type(8))) short short8;
typedef __attribute__((ext_vector_type(4))) float floatx4;
typedef unsigned short u16;

// fp32 -> bf16 (RNE), bit-level, no hip_bf16 dependency
__device__ inline u16 f2bf(float x) {
  unsigned u = __builtin_bit_cast(unsigned, x);
  unsigned r = u + 0x7fff + ((u >> 16) & 1);
  return (u16)(r >> 16);
}

__device__ inline void gll16(const void* g, void* l) {
  __builtin_amdgcn_global_load_lds((const __attribute__((address_space(1))) void*)g,
                                   (__attribute__((address_space(3))) void*)l, 16, 0, 0);
}

// ---------------- fp32 -> bf16 convert ----------------
__global__ void cvt_kernel(const float* __restrict__ src, u16* __restrict__ dst, int n) {
  int i = ((int)blockIdx.x * (int)blockDim.x + (int)threadIdx.x) * 4;
  if (i >= n) return;
  const float4 v = *(const float4*)(src + i);
  u16 h[4];
  h[0] = f2bf(v.x); h[1] = f2bf(v.y); h[2] = f2bf(v.z); h[3] = f2bf(v.w);
  uint64_t packed;
  __builtin_memcpy(&packed, h, 8);
  *(uint64_t*)(dst + i) = packed;
}

// ---------------- QKV projection GEMM ----------------
// X: [8192][512] bf16 row-major; W: [512][512] bf16 (row n, col k) == B^T form.
// z=0: Qp[(b*8+h)*S*64 + s*64 + d] = (x@Wq.T + bq)*0.125  (pre-scaled)
// z=1: Kp same layout, no scale
// z=2: Vt[(b*8+h)*64*S + d*S + s]  (transposed for attention B-frag reads)
__global__ __launch_bounds__(256) void gemm_qkv(
    const u16* __restrict__ Xq, const u16* __restrict__ Xk, const u16* __restrict__ Xv,
    const u16* __restrict__ Wb,
    const float* __restrict__ bq, const float* __restrict__ bk, const float* __restrict__ bv,
    u16* __restrict__ Qp, u16* __restrict__ Kp, u16* __restrict__ Vt) {
  const int z = blockIdx.z;
  const u16* X = (z == 0) ? Xq : ((z == 1) ? Xk : Xv);
  const u16* W = Wb + (size_t)z * (HID * HID);
  const float* bias = (z == 0) ? bq : ((z == 1) ? bk : bv);

  __shared__ u16 As[128 * 32];
  __shared__ u16 Bs[128 * 32];

  const int tid = threadIdx.x;
  const int wid = tid >> 6, lane = tid & 63;
  const int wm = wid >> 1, wn = wid & 1;
  const int quad = lane >> 4, l16 = lane & 15;
  const int m0 = (int)blockIdx.x * 128, n0 = (int)blockIdx.y * 128;
  const int srow = lane >> 2;        // 4 lanes per 32-elem row (16B each)
  const int scol = (lane & 3) * 8;

  floatx4 acc[4][4];
#pragma unroll
  for (int i = 0; i < 4; i++)
#pragma unroll
    for (int j = 0; j < 4; j++) acc[i][j] = floatx4{0.f, 0.f, 0.f, 0.f};

  for (int k0 = 0; k0 < HID; k0 += 32) {
#pragma unroll
    for (int r = 0; r < 2; r++) {
      int row = r * 64 + wid * 16 + srow;
      gll16(X + (size_t)(m0 + row) * HID + k0 + scol, &As[(r * 64 + wid * 16) * 32]);
      gll16(W + (size_t)(n0 + row) * HID + k0 + scol, &Bs[(r * 64 + wid * 16) * 32]);
    }
    __syncthreads();
    short8 af[4], bf[4];
#pragma unroll
    for (int mt = 0; mt < 4; mt++)
      af[mt] = *(const short8*)&As[(wm * 64 + mt * 16 + l16) * 32 + quad * 8];
#pragma unroll
    for (int nt = 0; nt < 4; nt++)
      bf[nt] = *(const short8*)&Bs[(wn * 64 + nt * 16 + l16) * 32 + quad * 8];
#pragma unroll
    for (int mt = 0; mt < 4; mt++)
#pragma unroll
      for (int nt = 0; nt < 4; nt++)
        acc[mt][nt] = __builtin_amdgcn_mfma_f32_16x16x32_bf16(af[mt], bf[nt], acc[mt][nt], 0, 0, 0);
    __syncthreads();
  }

#pragma unroll
  for (int mt = 0; mt < 4; mt++) {
#pragma unroll
    for (int nt = 0; nt < 4; nt++) {
      int ncol = n0 + wn * 64 + nt * 16 + l16;
      float bias_v = bias[ncol];
      int h = ncol >> 6, d = ncol & 63;
#pragma unroll
      for (int r = 0; r < 4; r++) {
        int mrow = m0 + wm * 64 + mt * 16 + quad * 4 + r;
        float v = acc[mt][nt][r] + bias_v;
        int b = mrow >> 12, s = mrow & (SEQ - 1);
        int bh = b * NH + h;
        if (z == 0)      Qp[((size_t)bh * SEQ + s) * HD + d] = f2bf(v * 0.125f);
        else if (z == 1) Kp[((size_t)bh * SEQ + s) * HD + d] = f2bf(v);
        else             Vt[((size_t)bh * HD + d) * SEQ + s] = f2bf(v);
      }
    }
  }
}

// ---------------- output projection GEMM (fp32 epilogue) ----------------
__global__ __launch_bounds__(256) void gemm_out(
    const u16* __restrict__ X, const u16* __restrict__ W,
    const float* __restrict__ bias, float* __restrict__ out) {
  __shared__ u16 As[128 * 32];
  __shared__ u16 Bs[128 * 32];

  const int tid = threadIdx.x;
  const int wid = tid >> 6, lane = tid & 63;
  const int wm = wid >> 1, wn = wid & 1;
  const int quad = lane >> 4, l16 = lane & 15;
  const int m0 = (int)blockIdx.x * 128, n0 = (int)blockIdx.y * 128;
  const int srow = lane >> 2;
  const int scol = (lane & 3) * 8;

  floatx4 acc[4][4];
#pragma unroll
  for (int i = 0; i < 4; i++)
#pragma unroll
    for (int j = 0; j < 4; j++) acc[i][j] = floatx4{0.f, 0.f, 0.f, 0.f};

  for (int k0 = 0; k0 < HID; k0 += 32) {
#pragma unroll
    for (int r = 0; r < 2; r++) {
      int row = r * 64 + wid * 16 + srow;
      gll16(X + (size_t)(m0 + row) * HID + k0 + scol, &As[(r * 64 + wid * 16) * 32]);
      gll16(W + (size_t)(n0 + row) * HID + k0 + scol, &Bs[(r * 64 + wid * 16) * 32]);
    }
    __syncthreads();
    short8 af[4], bf[4];
#pragma unroll
    for (int mt = 0; mt < 4; mt++)
      af[mt] = *(const short8*)&As[(wm * 64 + mt * 16 + l16) * 32 + quad * 8];
#pragma unroll
    for (int nt = 0; nt < 4; nt++)
      bf[nt] = *(const short8*)&Bs[(wn * 64 + nt * 16 + l16) * 32 + quad * 8];
#pragma unroll
    for (int mt = 0; mt < 4; mt++)
#pragma unroll
      for (int nt = 0; nt < 4; nt++)
        acc[mt][nt] = __builtin_amdgcn_mfma_f32_16x16x32_bf16(af[mt], bf[nt], acc[mt][nt], 0, 0, 0);
    __syncthreads();
  }

#pragma unroll
  for (int mt = 0; mt < 4; mt++) {
#pragma unroll
    for (int nt = 0; nt < 4; nt++) {
      int ncol = n0 + wn * 64 + nt * 16 + l16;
      float bias_v = bias[ncol];
#pragma unroll
      for (int r = 0; r < 4; r++) {
        int mrow = m0 + wm * 64 + mt * 16 + quad * 4 + r;
        out[(size_t)mrow * HID + ncol] = acc[mt][nt][r] + bias_v;
      }
    }
  }
}

// ---------------- flash attention ----------------
// Qp/Kp: [BH][S][64] bf16 (Q pre-scaled by 1/8); Vt: [BH][64][S] bf16
// Xo: [B][S][512] bf16  (re-fused heads, ready for out-proj GEMM)
__global__ __launch_bounds__(256) void attn_kernel(
    const u16* __restrict__ Qp, const u16* __restrict__ Kp,
    const u16* __restrict__ Vt, u16* __restrict__ Xo) {
  const int bh = blockIdx.y;
  const int q0 = (int)blockIdx.x * 64;
  const u16* Qh = Qp + (size_t)bh * SEQ * HD;
  const u16* Kh = Kp + (size_t)bh * SEQ * HD;
  const u16* Vh = Vt + (size_t)bh * HD * SEQ;

  __shared__ u16 Qs[64 * 64];
  __shared__ u16 Ks[64 * 64];
  __shared__ u16 Vs[64 * 64];   // d-major: Vs[d][kv]
  __shared__ u16 Ps[64 * 64];

  const int tid = threadIdx.x;
  const int wid = tid >> 6, lane = tid & 63;
  const int quad = lane >> 4, l16 = lane & 15;
  const int srow = lane >> 3;        // 8 lanes per 64-elem row
  const int scol = (lane & 7) * 8;

  // stage Q tile once
#pragma unroll
  for (int r = 0; r < 2; r++) {
    int row = wid * 16 + r * 8 + srow;
    gll16(Qh + (size_t)(q0 + row) * HD + scol, &Qs[(wid * 16 + r * 8) * 64]);
  }
  __syncthreads();
  short8 aq[2];
#pragma unroll
  for (int kq = 0; kq < 2; kq++)
    aq[kq] = *(const short8*)&Qs[(wid * 16 + l16) * 64 + kq * 32 + quad * 8];

  float m_i[4], l_i[4];
  floatx4 o[4];
#pragma unroll
  for (int r = 0; r < 4; r++) { m_i[r] = -1e30f; l_i[r] = 0.f; }
#pragma unroll
  for (int dt = 0; dt < 4; dt++) o[dt] = floatx4{0.f, 0.f, 0.f, 0.f};

  for (int kv0 = 0; kv0 < SEQ; kv0 += 64) {
    __syncthreads();   // previous iter's LDS reads done before overwrite
#pragma unroll
    for (int r = 0; r < 2; r++) {
      int row = wid * 16 + r * 8 + srow;
      gll16(Kh + (size_t)(kv0 + row) * HD + scol, &Ks[(wid * 16 + r * 8) * 64]);
      gll16(Vh + (size_t)row * SEQ + kv0 + scol, &Vs[(wid * 16 + r * 8) * 64]);
    }
    __syncthreads();

    // S = Q K^T (Q pre-scaled): wave strip = 16 q-rows x 64 kv-cols
    floatx4 sacc[4];
#pragma unroll
    for (int nt = 0; nt < 4; nt++) sacc[nt] = floatx4{0.f, 0.f, 0.f, 0.f};
#pragma unroll
    for (int kq = 0; kq < 2; kq++) {
#pragma unroll
      for (int nt = 0; nt < 4; nt++) {
        short8 bk_ = *(const short8*)&Ks[(nt * 16 + l16) * 64 + kq * 32 + quad * 8];
        sacc[nt] = __builtin_amdgcn_mfma_f32_16x16x32_bf16(aq[kq], bk_, sacc[nt], 0, 0, 0);
      }
    }

    // online softmax: row = quad*4 + r
    float alpha[4];
#pragma unroll
    for (int r = 0; r < 4; r++) {
      float mx = fmaxf(fmaxf(sacc[0][r], sacc[1][r]), fmaxf(sacc[2][r], sacc[3][r]));
#pragma unroll
      for (int m = 1; m < 16; m <<= 1) mx = fmaxf(mx, __shfl_xor(mx, m));
      float mnew = fmaxf(m_i[r], mx);
      alpha[r] = __expf(m_i[r] - mnew);
      m_i[r] = mnew;
      float sum = 0.f;
#pragma unroll
      for (int nt = 0; nt < 4; nt++) {
        float p = __expf(sacc[nt][r] - mnew);
        sacc[nt][r] = p;
        sum += p;
      }
#pragma unroll
      for (int m = 1; m < 16; m <<= 1) sum += __shfl_xor(sum, m);
      l_i[r] = l_i[r] * alpha[r] + sum;
    }

    // P (C-layout) -> LDS (A-layout source); rescale O
#pragma unroll
    for (int nt = 0; nt < 4; nt++)
#pragma unroll
      for (int r = 0; r < 4; r++)
        Ps[(wid * 16 + quad * 4 + r) * 64 + nt * 16 + l16] = f2bf(sacc[nt][r]);
#pragma unroll
    for (int dt = 0; dt < 4; dt++)
#pragma unroll
      for (int r = 0; r < 4; r++) o[dt][r] *= alpha[r];
    __syncthreads();   // conservative: ensure Ps writes visible before reads

    // O += P V  (B-frag from d-major Vs: contiguous b128 reads)
#pragma unroll
    for (int kk = 0; kk < 2; kk++) {
      short8 ap = *(const short8*)&Ps[(wid * 16 + l16) * 64 + kk * 32 + quad * 8];
#pragma unroll
      for (int dt = 0; dt < 4; dt++) {
        short8 bv_ = *(const short8*)&Vs[(dt * 16 + l16) * 64 + kk * 32 + quad * 8];
        o[dt] = __builtin_amdgcn_mfma_f32_16x16x32_bf16(ap, bv_, o[dt], 0, 0, 0);
      }
    }
  }

  // epilogue: normalize, fuse heads back to [B][S][512]
  const int b = bh >> 3, h = bh & 7;
#pragma unroll
  for (int r = 0; r < 4; r++) {
    float inv = 1.f / l_i[r];
    int s = q0 + wid * 16 + quad * 4 + r;
    size_t base = ((size_t)(b * SEQ + s)) * HID + h * HD;
#pragma unroll
    for (int dt = 0; dt < 4; dt++)
      Xo[base + dt * 16 + l16] = f2bf(o[dt][r] * inv);
  }
}

extern "C" void kernel_launch(void* const* d_in, const int* in_sizes, int n_in,
                              void* d_out, int out_size, void* d_ws, size_t ws_size,
                              hipStream_t stream) {
  const float* q  = (const float*)d_in[0];
  const float* k  = (const float*)d_in[1];
  const float* v  = (const float*)d_in[2];
  const float* Wq = (const float*)d_in[3];
  const float* bq = (const float*)d_in[4];
  const float* Wk = (const float*)d_in[5];
  const float* bk = (const float*)d_in[6];
  const float* Wv = (const float*)d_in[7];
  const float* bv = (const float*)d_in[8];
  const float* Wo = (const float*)d_in[9];
  const float* bo = (const float*)d_in[10];

  u16* wsb = (u16*)d_ws;
  const size_t NW = (size_t)HID * HID;     // 262144
  const size_t NX = (size_t)M_TOT * HID;   // 4194304
  u16* Wb = wsb;            // Wq,Wk,Wv,Wo bf16 (4*NW)
  u16* Xq = wsb + 4 * NW;
  u16* Xk = Xq + NX;
  u16* Xv = Xk + NX;
  u16* Qp = Xv + NX;
  u16* Kp = Qp + NX;
  u16* Vt = Kp + NX;
  u16* Xo = Vt + NX;        // total ~58 MB of d_ws

  dim3 blk(256);
  cvt_kernel<<<dim3((unsigned)((NX / 4 + 255) / 256)), blk, 0, stream>>>(q, Xq, (int)NX);
  cvt_kernel<<<dim3((unsigned)((NX / 4 + 255) / 256)), blk, 0, stream>>>(k, Xk, (int)NX);
  cvt_kernel<<<dim3((unsigned)((NX / 4 + 255) / 256)), blk, 0, stream>>>(v, Xv, (int)NX);
  cvt_kernel<<<dim3((unsigned)((NW / 4 + 255) / 256)), blk, 0, stream>>>(Wq, Wb + 0 * NW, (int)NW);
  cvt_kernel<<<dim3((unsigned)((NW / 4 + 255) / 256)), blk, 0, stream>>>(Wk, Wb + 1 * NW, (int)NW);
  cvt_kernel<<<dim3((unsigned)((NW / 4 + 255) / 256)), blk, 0, stream>>>(Wv, Wb + 2 * NW, (int)NW);
  cvt_kernel<<<dim3((unsigned)((NW / 4 + 255) / 256)), blk, 0, stream>>>(Wo, Wb + 3 * NW, (int)NW);

  gemm_qkv<<<dim3(64, 4, 3), blk, 0, stream>>>(Xq, Xk, Xv, Wb, bq, bk, bv, Qp, Kp, Vt);
  attn_kernel<<<dim3(64, 16), blk, 0, stream>>>(Qp, Kp, Vt, Xo);
  gemm_out<<<dim3(64, 4), blk, 0, stream>>>(Xo, Wb + 3 * NW, bo, (float*)d_out);
}